// Round 20
// baseline (1061.809 us; speedup 1.0000x reference)
//
#include <hip/hip_runtime.h>

#define T_LEN 4096
#define C_DIM 2048
#define REC 224          // packed record: 16x[a,b,k,r] bf16 128B | dec/y f32 64B | v bf16 32B
#define CH 64            // scan steps per LDS chunk (64*224 = 14336 B)
#define CHB (CH * REC)

typedef __attribute__((ext_vector_type(4))) float f32x4;
typedef __attribute__((ext_vector_type(8))) __bf16 bf16x8;
typedef __attribute__((ext_vector_type(8))) unsigned short u16x8;
typedef __attribute__((ext_vector_type(4))) unsigned int u32x4;
typedef __attribute__((ext_vector_type(2))) unsigned int u32x2;
typedef unsigned short u16;
typedef unsigned int u32;

typedef __attribute__((address_space(1))) const void* as1cv;
typedef __attribute__((address_space(3))) void* as3v;

__device__ __forceinline__ void gld16(const void* g, void* l) {
  __builtin_amdgcn_global_load_lds((as1cv)g, (as3v)l, 16, 0, 0);
}

__device__ __forceinline__ u16 f2bf(float f) {
  union { float f; unsigned u; } x; x.f = f;
  return (u16)((x.u + 0x7fffu + ((x.u >> 16) & 1u)) >> 16);
}
__device__ __forceinline__ float bflo(unsigned u) {
  union { unsigned u; float f; } x; x.u = u << 16; return x.f;
}
__device__ __forceinline__ float bfhi(unsigned u) {
  union { unsigned u; float f; } x; x.u = u & 0xffff0000u; return x.f;
}
// sum over a 16-lane row via DPP (xor1, xor2, row_ror:4, row_ror:8) — all lanes get the sum
__device__ __forceinline__ float red16(float x) {
  int a;
  a = __builtin_amdgcn_update_dpp(0, __builtin_bit_cast(int, x), 0xB1, 0xF, 0xF, true);
  x += __builtin_bit_cast(float, a);
  a = __builtin_amdgcn_update_dpp(0, __builtin_bit_cast(int, x), 0x4E, 0xF, 0xF, true);
  x += __builtin_bit_cast(float, a);
  a = __builtin_amdgcn_update_dpp(0, __builtin_bit_cast(int, x), 0x124, 0xF, 0xF, true);
  x += __builtin_bit_cast(float, a);
  a = __builtin_amdgcn_update_dpp(0, __builtin_bit_cast(int, x), 0x128, 0xF, 0xF, true);
  x += __builtin_bit_cast(float, a);
  return x;
}
__device__ __forceinline__ f32x4 red16v(f32x4 v) {
  v[0] = red16(v[0]); v[1] = red16(v[1]);
  v[2] = red16(v[2]); v[3] = red16(v[3]);
  return v;
}

// ---------------- weights fp32 -> bf16 (all four in one launch) ----------------
__global__ __launch_bounds__(256)
void conv_bf16_k(const float* __restrict__ s0, const float* __restrict__ s1,
                 const float* __restrict__ s2, const float* __restrict__ s3,
                 u16* __restrict__ d0) {
  const float* s = (blockIdx.y == 0) ? s0 : (blockIdx.y == 1) ? s1
                   : (blockIdx.y == 2) ? s2 : s3;
  u16* d = d0 + (size_t)blockIdx.y * 4194304;
  int i = (blockIdx.x * 256 + threadIdx.x) * 8;
  f32x4 a = *(const f32x4*)(s + i);
  f32x4 b = *(const f32x4*)(s + i + 4);
  u16x8 o;
  o[0] = f2bf(a[0]); o[1] = f2bf(a[1]); o[2] = f2bf(a[2]); o[3] = f2bf(a[3]);
  o[4] = f2bf(b[0]); o[5] = f2bf(b[1]); o[6] = f2bf(b[2]); o[7] = f2bf(b[3]);
  *(u16x8*)(d + i) = o;
}

// ---------------- LoRA-down matrices: (C x 8) -> (8 x C) fp32 transpose ----------------
__global__ __launch_bounds__(256)
void trans_lora_k(const float* __restrict__ w1, const float* __restrict__ a1,
                  const float* __restrict__ v1, const float* __restrict__ g1,
                  float* __restrict__ wt) {
  const float* s = (blockIdx.y == 0) ? w1 : (blockIdx.y == 1) ? a1
                   : (blockIdx.y == 2) ? v1 : g1;
  float* d = wt + (size_t)blockIdx.y * (8 * C_DIM);
  int c = blockIdx.x * 256 + threadIdx.x;    // grid.x = 8
  f32x4 lo = *(const f32x4*)(s + c * 8);
  f32x4 hi = *(const f32x4*)(s + c * 8 + 4);
  d[0 * C_DIM + c] = lo[0]; d[1 * C_DIM + c] = lo[1];
  d[2 * C_DIM + c] = lo[2]; d[3 * C_DIM + c] = lo[3];
  d[4 * C_DIM + c] = hi[0]; d[5 * C_DIM + c] = hi[1];
  d[6 * C_DIM + c] = hi[2]; d[7 * C_DIM + c] = hi[3];
}

// ---------------- mix + LoRA down: 2 rows per block (tables read once per pair) ----------------
__global__ __launch_bounds__(256)
void mix_lora_k(const float* __restrict__ x,
                const float* __restrict__ xrw, const float* __restrict__ xww,
                const float* __restrict__ xkw, const float* __restrict__ xvw,
                const float* __restrict__ xaw, const float* __restrict__ xgw,
                const float* __restrict__ wt,   // 4 transposed tables, 8xC each
                u16* __restrict__ xr_bf, u16* __restrict__ xk_bf,
                u16* __restrict__ xv_bf, float* __restrict__ lora8) {
  const int pr = blockIdx.x * 2;          // rows pr, pr+1 (t0 even)
  const int t0 = pr & (T_LEN - 1);
  const int tid = threadIdx.x;
  const float* xr0 = x + (size_t)pr * C_DIM;
  const float* xr1 = xr0 + C_DIM;
  float wl0[8], al0[8], vl0[8], gl0[8];
  float wl1[8], al1[8], vl1[8], gl1[8];
  #pragma unroll
  for (int l = 0; l < 8; ++l) {
    wl0[l] = 0.f; al0[l] = 0.f; vl0[l] = 0.f; gl0[l] = 0.f;
    wl1[l] = 0.f; al1[l] = 0.f; vl1[l] = 0.f; gl1[l] = 0.f;
  }
  #pragma unroll
  for (int ii = 0; ii < 8; ++ii) {
    const int c = ii * 256 + tid;
    float x0 = xr0[c], x1 = xr1[c];
    float xm = t0 ? xr0[c - C_DIM] : 0.f;
    float dx0 = xm - x0;
    float dx1 = x0 - x1;
    float mr = xrw[c], mw = xww[c], mk = xkw[c];
    float mv = xvw[c], ma = xaw[c], mg = xgw[c];
    float xw0 = fmaf(dx0, mw, x0), xw1 = fmaf(dx1, mw, x1);
    float xa0 = fmaf(dx0, ma, x0), xa1 = fmaf(dx1, ma, x1);
    float xv0 = fmaf(dx0, mv, x0), xv1 = fmaf(dx1, mv, x1);
    float xg0 = fmaf(dx0, mg, x0), xg1 = fmaf(dx1, mg, x1);
    xr_bf[(size_t)pr * C_DIM + c] = f2bf(fmaf(dx0, mr, x0));
    xr_bf[(size_t)(pr + 1) * C_DIM + c] = f2bf(fmaf(dx1, mr, x1));
    xk_bf[(size_t)pr * C_DIM + c] = f2bf(fmaf(dx0, mk, x0));
    xk_bf[(size_t)(pr + 1) * C_DIM + c] = f2bf(fmaf(dx1, mk, x1));
    xv_bf[(size_t)pr * C_DIM + c] = f2bf(xv0);
    xv_bf[(size_t)(pr + 1) * C_DIM + c] = f2bf(xv1);
    #pragma unroll
    for (int l = 0; l < 8; ++l) {
      float tw = wt[l * C_DIM + c];
      float ta = wt[16384 + l * C_DIM + c];
      float tv = wt[32768 + l * C_DIM + c];
      float tg = wt[49152 + l * C_DIM + c];
      wl0[l] = fmaf(xw0, tw, wl0[l]); wl1[l] = fmaf(xw1, tw, wl1[l]);
      al0[l] = fmaf(xa0, ta, al0[l]); al1[l] = fmaf(xa1, ta, al1[l]);
      vl0[l] = fmaf(xv0, tv, vl0[l]); vl1[l] = fmaf(xv1, tv, vl1[l]);
      gl0[l] = fmaf(xg0, tg, gl0[l]); gl1[l] = fmaf(xg1, tg, gl1[l]);
    }
  }
  __shared__ __attribute__((aligned(16))) float red2[2][16][32];
  const int row = tid >> 4;
  // row-reduce (16 lanes) all partials via DPP — pure VALU
  f32x4 t0v, t1v;
  #pragma unroll
  for (int half = 0; half < 2; ++half) {
    float* wl = half ? wl1 : wl0;
    float* al = half ? al1 : al0;
    float* vl = half ? vl1 : vl0;
    float* gl = half ? gl1 : gl0;
    t0v = red16v((f32x4){wl[0], wl[1], wl[2], wl[3]});
    t1v = red16v((f32x4){wl[4], wl[5], wl[6], wl[7]});
    if ((tid & 15) == 0) {
      *(f32x4*)&red2[half][row][0] = t0v; *(f32x4*)&red2[half][row][4] = t1v;
    }
    t0v = red16v((f32x4){al[0], al[1], al[2], al[3]});
    t1v = red16v((f32x4){al[4], al[5], al[6], al[7]});
    if ((tid & 15) == 0) {
      *(f32x4*)&red2[half][row][8] = t0v; *(f32x4*)&red2[half][row][12] = t1v;
    }
    t0v = red16v((f32x4){vl[0], vl[1], vl[2], vl[3]});
    t1v = red16v((f32x4){vl[4], vl[5], vl[6], vl[7]});
    if ((tid & 15) == 0) {
      *(f32x4*)&red2[half][row][16] = t0v; *(f32x4*)&red2[half][row][20] = t1v;
    }
    t0v = red16v((f32x4){gl[0], gl[1], gl[2], gl[3]});
    t1v = red16v((f32x4){gl[4], gl[5], gl[6], gl[7]});
    if ((tid & 15) == 0) {
      *(f32x4*)&red2[half][row][24] = t0v; *(f32x4*)&red2[half][row][28] = t1v;
    }
  }
  __syncthreads();
  if (tid < 64) {
    const int rw = tid >> 5, idx = tid & 31;
    float s = 0.f;
    #pragma unroll
    for (int r = 0; r < 16; ++r) s += red2[rw][r][idx];
    int mat = idx >> 3;
    if (mat == 0) s = tanhf(s);
    else if (mat == 3) s = 1.f / (1.f + expf(-s));
    lora8[(size_t)(pr + rw) * 32 + idx] = s;
  }
}

// ---------------- 256x256 8-wave MFMA GEMM: BK=32, double buffer (64KB -> 2 blocks/CU) ----------------
// Scatter staging: k -> bytes 128..159, r -> 160..191, v -> 192..223 of the
// record (all 32B-contiguous; dec/y slot doubles as k/r staging until
// post_gemm consumes it).
__device__ __forceinline__ int swzslot(int row, int slot) {
  return slot ^ ((row >> 1) & 3);
}

__global__ __launch_bounds__(512)
void gemm8_k(const u16* __restrict__ A0, const u16* __restrict__ A1,
             const u16* __restrict__ A2, const u16* __restrict__ B0,
             const u16* __restrict__ B1, const u16* __restrict__ B2,
             char* __restrict__ out, int pmode) {
  extern __shared__ __attribute__((aligned(16))) char smem[];
  // 2 buffers x 32 KB; buffer b: A u16[8192] at b*16384, B u16[8192] at +8192
  const int z = blockIdx.z;
  const u16* A = (z == 0) ? A0 : (z == 1) ? A1 : A2;
  const u16* Bw = (z == 0) ? B0 : (z == 1) ? B1 : B2;
  const int sbase = (z == 0) ? 128 : (z == 1) ? 160 : 192;
  const int tid = threadIdx.x;
  const int wv = tid >> 6, ln = tid & 63;
  const int wr = wv >> 2, wc = wv & 3;         // 2 x 4 wave grid
  // XCD-bijective swizzle of the 8x32 tile grid (nwg=256, 256%8==0)
  const int bid = blockIdx.x + (blockIdx.y << 3);
  const int sw = (bid & 7) * 32 + (bid >> 3);
  const int row0 = (sw >> 3) * 256, col0 = (sw & 7) * 256;
  const int s_rw = tid >> 2;
  const int s_slotL = (tid & 3) ^ ((s_rw >> 1) & 3);   // logical slot fetched
  int aoff[8], boff[4];
  #pragma unroll
  for (int m = 0; m < 8; ++m) {
    int row = wr * 128 + m * 16 + (ln & 15);
    aoff[m] = row * 32 + swzslot(row, ln >> 4) * 8;
  }
  #pragma unroll
  for (int n = 0; n < 4; ++n) {
    int row = wc * 64 + n * 16 + (ln & 15);
    boff[n] = row * 32 + swzslot(row, ln >> 4) * 8;
  }
  f32x4 acc[8][4];
  #pragma unroll
  for (int m = 0; m < 8; ++m)
    #pragma unroll
    for (int n = 0; n < 4; ++n) acc[m][n] = (f32x4){0.f, 0.f, 0.f, 0.f};

  auto bufA = [&](int b) -> u16* { return (u16*)smem + b * 16384; };
  auto bufB = [&](int b) -> u16* { return (u16*)smem + b * 16384 + 8192; };
  auto stageA = [&](int kt, int b, int rblk) {
    const u16* g = A + (size_t)(row0 + rblk * 128 + s_rw) * 2048 + kt * 32 + s_slotL * 8;
    gld16(g, bufA(b) + rblk * 4096 + wv * 512);
  };
  auto stageB = [&](int kt, int b, int rblk) {
    const u16* g = Bw + (size_t)(col0 + rblk * 128 + s_rw) * 2048 + kt * 32 + s_slotL * 8;
    gld16(g, bufB(b) + rblk * 4096 + wv * 512);
  };

  // prologue: tile 0 into buffer 0
  stageA(0, 0, 0); stageA(0, 0, 1); stageB(0, 0, 0); stageB(0, 0, 1);

  for (int kt = 0; kt < 64; ++kt) {
    asm volatile("s_waitcnt vmcnt(0)" ::: "memory");
    __builtin_amdgcn_s_barrier();
    const int b = kt & 1;
    const u16* Ab = bufA(b);
    const u16* Bb = bufB(b);
    const int b1 = b ^ 1;
    const bool st = kt < 63;
    bf16x8 bf[4], af[4];
    #pragma unroll
    for (int n = 0; n < 4; ++n) bf[n] = *(const bf16x8*)(Bb + boff[n]);
    #pragma unroll
    for (int m = 0; m < 4; ++m) af[m] = *(const bf16x8*)(Ab + aoff[m]);
    if (st) { stageA(kt + 1, b1, 0); stageA(kt + 1, b1, 1); }
    __builtin_amdgcn_s_setprio(1);
    #pragma unroll
    for (int m = 0; m < 4; ++m)
      #pragma unroll
      for (int n = 0; n < 4; ++n)
        acc[m][n] = __builtin_amdgcn_mfma_f32_16x16x32_bf16(af[m], bf[n], acc[m][n], 0, 0, 0);
    __builtin_amdgcn_s_setprio(0);
    #pragma unroll
    for (int m = 0; m < 4; ++m) af[m] = *(const bf16x8*)(Ab + aoff[4 + m]);
    if (st) { stageB(kt + 1, b1, 0); stageB(kt + 1, b1, 1); }
    __builtin_amdgcn_s_setprio(1);
    #pragma unroll
    for (int m = 0; m < 4; ++m)
      #pragma unroll
      for (int n = 0; n < 4; ++n)
        acc[4 + m][n] = __builtin_amdgcn_mfma_f32_16x16x32_bf16(af[m], bf[n], acc[4 + m][n], 0, 0, 0);
    __builtin_amdgcn_s_setprio(0);
  }

  const int rowb = row0 + wr * 128 + ((ln >> 4) << 2);
  const int colb = col0 + wc * 64 + (ln & 15);
  #pragma unroll
  for (int m = 0; m < 8; ++m)
    #pragma unroll
    for (int n = 0; n < 4; ++n)
      #pragma unroll
      for (int qq = 0; qq < 4; ++qq) {
        int row = rowb + m * 16 + qq;
        int col = colb + n * 16;
        float val = acc[m][n][qq];
        if (pmode == 0) {
          ((float*)out)[(size_t)row * 2048 + col] = val;
        } else {
          int bq = row >> 12, tq = row & (T_LEN - 1);
          int hq = col >> 4, jq = col & 15;
          *(u16*)(out + (size_t)((bq * 128 + hq) * T_LEN + tq) * REC
                  + sbase + jq * 2) = f2bf(val);
        }
      }
}

// ---------------- post-GEMM: LoRA-up, decay, v-mix, kk-norm (coalesced module mapping) ----------------
// Reads k/r/v from staging (k@128, r@160, v@192), assembles packets, writes
// dec over the staging. Record's 16 channels live in one 16-lane group, so
// wave-lockstep orders staging reads before the dec overwrite.
__global__ __launch_bounds__(256)
void post_gemm_k(const float* __restrict__ v_first, const float* __restrict__ lora8,
                 const float* __restrict__ w0, const float* __restrict__ w2,
                 const float* __restrict__ a0, const float* __restrict__ a2,
                 const float* __restrict__ v0, const float* __restrict__ v2,
                 const float* __restrict__ k_k, const float* __restrict__ k_a,
                 char* __restrict__ packed) {
  const int tg = blockIdx.x;          // 0..1023 (4 t each)
  const int mo = blockIdx.y;          // module 0..31 (64 channels)
  const int bq = blockIdx.z;
  const int tid = threadIdx.x;
  const int wv = tid >> 6, ln = tid & 63;
  const int t = tg * 4 + wv;
  const int cc = ln & 15;
  const int hq = mo * 4 + (ln >> 4);
  const int c = mo * 64 + ln;
  char* pb = packed + (size_t)((bq * 128 + hq) * T_LEN + t) * REC;
  const int rr = bq * T_LEN + t;
  u32 kbits = *(const u16*)(pb + 128 + cc * 2);   // k staging
  u32 rbits = *(const u16*)(pb + 160 + cc * 2);   // r staging
  float kraw = bflo(kbits);
  float vraw = bflo(*(const u16*)(pb + 192 + cc * 2));
  float vf = v_first[(size_t)rr * C_DIM + c];
  const float* lo = lora8 + (size_t)rr * 32;
  float wr_ = w0[c], ar_ = a0[c], vr_ = v0[c];
  #pragma unroll
  for (int l = 0; l < 8; ++l) {
    wr_ = fmaf(lo[l], w2[l * C_DIM + c], wr_);
    ar_ = fmaf(lo[8 + l], a2[l * C_DIM + c], ar_);
    vr_ = fmaf(lo[16 + l], v2[l * C_DIM + c], vr_);
  }
  float w_ = -log1pf(expf(-wr_)) - 0.5f;
  float dec = expf(-expf(w_));
  float a_ = 1.f / (1.f + expf(-ar_));
  float vm = 1.f / (1.f + expf(-vr_));
  float vnew = fmaf(vf - vraw, vm, vraw);
  float kk = kraw * k_k[c];
  float ss = red16(kk * kk);
  ss += __shfl_xor(ss, 16);
  ss += __shfl_xor(ss, 32);
  float sc = 1.f / fmaxf(sqrtf(ss), 1e-8f);
  float kn = kk * sc;
  u16 wa = f2bf(-kn);
  u16 wb = f2bf(kn * a_);
  u16 wk = f2bf(kraw * fmaf(a_ - 1.f, k_a[c], 1.f));
  // packets: word0 = a|b, word1 = k|r
  *(u32*)(pb + cc * 8) = (u32)wa | ((u32)wb << 16);
  *(u32*)(pb + cc * 8 + 4) = (u32)wk | (rbits << 16);
  *(u16*)(pb + 192 + cc * 2) = f2bf(vnew);
  *(float*)(pb + 128 + cc * 4) = dec;              // overwrites k/r staging
}

// ---------------- sequential RWKV7 scan: 1 head / 4-wave block, 1 elem/lane ----------------
__device__ __forceinline__ void stage(const char* g, char* l, int wv, int ln) {
  gld16(g + wv * 1024 + ln * 16, l + wv * 1024);
  gld16(g + 4096 + wv * 1024 + ln * 16, l + 4096 + wv * 1024);
  gld16(g + 8192 + wv * 1024 + ln * 16, l + 8192 + wv * 1024);
  if (wv < 2) gld16(g + 12288 + wv * 1024 + ln * 16, l + 12288 + wv * 1024);
}

__global__ __launch_bounds__(256)
void scan_k(char* __restrict__ packed) {
  // 2 chunk halves + 1 KB pad so distance-4 over-reads stay in-bounds
  __shared__ __attribute__((aligned(16))) char bufm[2 * CHB + 1024];
  __shared__ __attribute__((aligned(16))) float ybuf[CH * 20];   // stride 20: bank-conflict-free dump
  const int hb = blockIdx.x;
  const int tid = threadIdx.x;
  const int wv = tid >> 6, ln = tid & 63;
  const int j = ln & 15;
  const int i = wv * 4 + (ln >> 4);
  char* src = packed + (size_t)hb * (T_LEN * REC);
  float S = 0.f;
  stage(src, bufm, wv, ln);
  const int NC = T_LEN / CH;
  for (int c = 0; c < NC; ++c) {
    asm volatile("s_waitcnt vmcnt(0)" ::: "memory");
    __syncthreads();
    if (c + 1 < NC)
      stage(src + (size_t)(c + 1) * CHB, bufm + ((c + 1) & 1) * CHB, wv, ln);
    const char* Bp = bufm + (c & 1) * CHB;
    const char* p0 = Bp + j * 8;         // [a|b][k|r] packet, +t*REC
    const char* pd = Bp + 128 + j * 4;   // dec f32
    const char* pv = Bp + 192 + i * 2;   // v bf16
    // preload steps 0..3
    u32x2 kq[4]; float dq[4]; u32 vq[4];
    #pragma unroll
    for (int s = 0; s < 4; ++s) {
      kq[s] = *(const u32x2*)(p0 + s * REC);
      dq[s] = *(const float*)(pd + s * REC);
      vq[s] = *(const u16*)(pv + s * REC);
    }
    float yq0 = 0.f, yq1 = 0.f, yq2 = 0.f, yq3 = 0.f;
    #pragma unroll
    for (int t = 0; t < CH; ++t) {
      const int st = t & 3;
      u32x2 kc = kq[st]; float dc = dq[st]; u32 vc = vq[st];
      // prefetch t+4 (tail over-reads land in pad; re-preloaded next chunk)
      kq[st] = *(const u32x2*)(p0 + (t + 4) * REC);
      dq[st] = *(const float*)(pd + (t + 4) * REC);
      vq[st] = *(const u16*)(pv + (t + 4) * REC);
      float a_ = bflo(kc[0]), b_ = bfhi(kc[0]);
      float k_ = bflo(kc[1]), r_ = bfhi(kc[1]);
      float v_ = bflo(vc);
      float sa = red16(S * a_);
      S = fmaf(S, dc, fmaf(sa, b_, v_ * k_));
      float yv = red16(S * r_);
      const bool own = (j == (t & 15));
      if ((t >> 4) == 0)      yq0 = own ? yv : yq0;
      else if ((t >> 4) == 1) yq1 = own ? yv : yq1;
      else if ((t >> 4) == 2) yq2 = own ? yv : yq2;
      else                    yq3 = own ? yv : yq3;
    }
    // dump register y to ybuf: value yqQ holds y for (t = Q*16 + j, row i)
    ybuf[(0 * 16 + j) * 20 + i] = yq0;
    ybuf[(1 * 16 + j) * 20 + i] = yq1;
    ybuf[(2 * 16 + j) * 20 + i] = yq2;
    ybuf[(3 * 16 + j) * 20 + i] = yq3;
    __syncthreads();
    // coalesced y flush: thread -> record tid>>2, 16B part tid&3
    {
      const int rec = tid >> 2, part = tid & 3;
      f32x4 y4 = *(const f32x4*)(ybuf + rec * 20 + part * 4);
      *(f32x4*)(src + (size_t)c * CHB + rec * REC + 128 + part * 16) = y4;
    }
  }
}

// ---------------- GroupNorm + residual + gate -> bf16 (coalesced module mapping) ----------------
__global__ __launch_bounds__(256)
void post_gn_k(const char* __restrict__ packed, const float* __restrict__ lora8,
               const float* __restrict__ g2, const float* __restrict__ ln_g,
               const float* __restrict__ ln_b, const float* __restrict__ r_k,
               u16* __restrict__ og) {
  const int tg = blockIdx.x;          // 0..1023 (4 t each)
  const int mo = blockIdx.y;          // module 0..31 (64 channels)
  const int bq = blockIdx.z;
  const int tid = threadIdx.x;
  const int wv = tid >> 6, ln = tid & 63;
  const int t = tg * 4 + wv;
  const int cc = ln & 15;
  const int hq = mo * 4 + (ln >> 4);
  const int c = mo * 64 + ln;
  const char* pb = packed + (size_t)((bq * 128 + hq) * T_LEN + t) * REC;
  u32 kr = *(const u32*)(pb + cc * 8 + 4);
  float kv = bflo(kr), rv = bfhi(kr);
  float vv = bflo(*(const u16*)(pb + 192 + cc * 2));
  float o = *(const float*)(pb + 128 + cc * 4);
  const int rr = bq * T_LEN + t;
  const float* lo = lora8 + (size_t)rr * 32 + 24;
  float gg = 0.f;
  #pragma unroll
  for (int l = 0; l < 8; ++l) gg = fmaf(lo[l], g2[l * C_DIM + c], gg);
  float s1 = red16(o);
  float s2 = red16(o * o);
  float srk = red16(rv * kv * r_k[c]);
  s1 += __shfl_xor(s1, 16); s2 += __shfl_xor(s2, 16); srk += __shfl_xor(srk, 16);
  s1 += __shfl_xor(s1, 32); s2 += __shfl_xor(s2, 32); srk += __shfl_xor(srk, 32);
  float mu = s1 * (1.f / 64.f);
  float var = s2 * (1.f / 64.f) - mu * mu;
  float rstd = rsqrtf(var + 0.00064f);
  float on = fmaf((o - mu) * rstd, ln_g[c], ln_b[c]);
  float o2 = fmaf(srk, vv, on);
  og[(size_t)rr * C_DIM + c] = f2bf(o2 * gg);
}

extern "C" void kernel_launch(void* const* d_in, const int* in_sizes, int n_in,
                              void* d_out, int out_size, void* d_ws, size_t ws_size,
                              hipStream_t stream) {
  (void)in_sizes; (void)n_in; (void)out_size;
  const float* x      = (const float*)d_in[0];
  const float* v_first= (const float*)d_in[1];
  const float* x_r    = (const float*)d_in[2];
  const float* x_w    = (const float*)d_in[3];
  const float* x_k    = (const float*)d_in[4];
  const float* x_v    = (const float*)d_in[5];
  const float* x_a    = (const float*)d_in[6];
  const float* x_g    = (const float*)d_in[7];
  const float* w0     = (const float*)d_in[8];
  const float* w1     = (const float*)d_in[9];
  const float* w2     = (const float*)d_in[10];
  const float* a0     = (const float*)d_in[11];
  const float* a1     = (const float*)d_in[12];
  const float* a2     = (const float*)d_in[13];
  const float* v0     = (const float*)d_in[14];
  const float* v1     = (const float*)d_in[15];
  const float* v2     = (const float*)d_in[16];
  const float* g1     = (const float*)d_in[17];
  const float* g2     = (const float*)d_in[18];
  const float* k_k    = (const float*)d_in[19];
  const float* k_a    = (const float*)d_in[20];
  const float* r_k    = (const float*)d_in[21];
  const float* Wr     = (const float*)d_in[22];
  const float* Wk     = (const float*)d_in[23];
  const float* Wv     = (const float*)d_in[24];
  const float* Wo     = (const float*)d_in[25];
  const float* ln_g   = (const float*)d_in[26];
  const float* ln_b   = (const float*)d_in[27];

  if (ws_size < 370147328ull) return;
  char* ws = (char*)d_ws;
  u16* Wr_bf = (u16*)(ws + 0);            //  8 MB each, contiguous (conv indexes)
  u16* Wk_bf = Wr_bf + 4194304;
  u16* Wv_bf = Wk_bf + 4194304;
  u16* Wo_bf = Wv_bf + 4194304;
  u16* xr_bf = (u16*)(ws + 33554432);     // 32 MB each
  u16* xk_bf = xr_bf + 16777216;
  u16* xv_bf = xk_bf + 16777216;
  float* lora8 = (float*)(ws + 134217728); // 1 MB
  char* packed = ws + 135266304;           // 224 MB
  float* wt = (float*)packed;              // transposed LoRA tables (256 KB),
                                           // consumed before gemms overwrite
  u16* og = xr_bf;                         // reuse (dead after r-GEMM)
  float* out = (float*)d_out;

  (void)hipFuncSetAttribute((const void*)gemm8_k,
                            hipFuncAttributeMaxDynamicSharedMemorySize, 65536);

  conv_bf16_k<<<dim3(2048, 4), 256, 0, stream>>>(Wr, Wk, Wv, Wo, Wr_bf);
  trans_lora_k<<<dim3(8, 4), 256, 0, stream>>>(w1, a1, v1, g1, wt);

  mix_lora_k<<<4096, 256, 0, stream>>>(x, x_r, x_w, x_k, x_v, x_a, x_g,
                                       wt, xr_bf, xk_bf, xv_bf, lora8);

  gemm8_k<<<dim3(8, 32, 3), 512, 65536, stream>>>(xk_bf, xr_bf, xv_bf,
                                                  Wk_bf, Wr_bf, Wv_bf,
                                                  packed, 1);

  post_gemm_k<<<dim3(1024, 32, 2), 256, 0, stream>>>(v_first, lora8, w0, w2,
                                                     a0, a2, v0, v2,
                                                     k_k, k_a, packed);

  scan_k<<<256, 256, 0, stream>>>(packed);

  post_gn_k<<<dim3(1024, 32, 2), 256, 0, stream>>>(packed, lora8, g2,
                                                   ln_g, ln_b, r_k, og);

  gemm8_k<<<dim3(8, 32, 1), 512, 65536, stream>>>(og, og, og,
                                                  Wo_bf, Wo_bf, Wo_bf,
                                                  (char*)out, 0);

  hipMemcpyAsync(out + 16777216, v_first, (size_t)16777216 * 4,
                 hipMemcpyDeviceToDevice, stream);
}

// Round 21
// 1026.176 us; speedup vs baseline: 1.0347x; 1.0347x over previous
//
#include <hip/hip_runtime.h>

#define T_LEN 4096
#define C_DIM 2048
#define REC 224          // packed record: 16x[a,b,k,r] bf16 128B | dec/y f32 64B | v bf16 32B
#define CH 64            // scan steps per LDS chunk (64*224 = 14336 B)
#define CHB (CH * REC)

typedef __attribute__((ext_vector_type(4))) float f32x4;
typedef __attribute__((ext_vector_type(8))) __bf16 bf16x8;
typedef __attribute__((ext_vector_type(8))) unsigned short u16x8;
typedef __attribute__((ext_vector_type(4))) unsigned int u32x4;
typedef __attribute__((ext_vector_type(2))) unsigned int u32x2;
typedef unsigned short u16;
typedef unsigned int u32;

typedef __attribute__((address_space(1))) const void* as1cv;
typedef __attribute__((address_space(3))) void* as3v;

__device__ __forceinline__ void gld16(const void* g, void* l) {
  __builtin_amdgcn_global_load_lds((as1cv)g, (as3v)l, 16, 0, 0);
}

__device__ __forceinline__ u16 f2bf(float f) {
  union { float f; unsigned u; } x; x.f = f;
  return (u16)((x.u + 0x7fffu + ((x.u >> 16) & 1u)) >> 16);
}
__device__ __forceinline__ float bflo(unsigned u) {
  union { unsigned u; float f; } x; x.u = u << 16; return x.f;
}
__device__ __forceinline__ float bfhi(unsigned u) {
  union { unsigned u; float f; } x; x.u = u & 0xffff0000u; return x.f;
}
// sum over a 16-lane row via DPP (xor1, xor2, row_ror:4, row_ror:8) — all lanes get the sum
__device__ __forceinline__ float red16(float x) {
  int a;
  a = __builtin_amdgcn_update_dpp(0, __builtin_bit_cast(int, x), 0xB1, 0xF, 0xF, true);
  x += __builtin_bit_cast(float, a);
  a = __builtin_amdgcn_update_dpp(0, __builtin_bit_cast(int, x), 0x4E, 0xF, 0xF, true);
  x += __builtin_bit_cast(float, a);
  a = __builtin_amdgcn_update_dpp(0, __builtin_bit_cast(int, x), 0x124, 0xF, 0xF, true);
  x += __builtin_bit_cast(float, a);
  a = __builtin_amdgcn_update_dpp(0, __builtin_bit_cast(int, x), 0x128, 0xF, 0xF, true);
  x += __builtin_bit_cast(float, a);
  return x;
}
__device__ __forceinline__ f32x4 red16v(f32x4 v) {
  v[0] = red16(v[0]); v[1] = red16(v[1]);
  v[2] = red16(v[2]); v[3] = red16(v[3]);
  return v;
}

// ---------------- weights fp32 -> bf16 (all four in one launch) ----------------
__global__ __launch_bounds__(256)
void conv_bf16_k(const float* __restrict__ s0, const float* __restrict__ s1,
                 const float* __restrict__ s2, const float* __restrict__ s3,
                 u16* __restrict__ d0) {
  const float* s = (blockIdx.y == 0) ? s0 : (blockIdx.y == 1) ? s1
                   : (blockIdx.y == 2) ? s2 : s3;
  u16* d = d0 + (size_t)blockIdx.y * 4194304;
  int i = (blockIdx.x * 256 + threadIdx.x) * 8;
  f32x4 a = *(const f32x4*)(s + i);
  f32x4 b = *(const f32x4*)(s + i + 4);
  u16x8 o;
  o[0] = f2bf(a[0]); o[1] = f2bf(a[1]); o[2] = f2bf(a[2]); o[3] = f2bf(a[3]);
  o[4] = f2bf(b[0]); o[5] = f2bf(b[1]); o[6] = f2bf(b[2]); o[7] = f2bf(b[3]);
  *(u16x8*)(d + i) = o;
}

// ---------------- LoRA-down matrices: (C x 8) -> (8 x C) fp32 transpose ----------------
__global__ __launch_bounds__(256)
void trans_lora_k(const float* __restrict__ w1, const float* __restrict__ a1,
                  const float* __restrict__ v1, const float* __restrict__ g1,
                  float* __restrict__ wt) {
  const float* s = (blockIdx.y == 0) ? w1 : (blockIdx.y == 1) ? a1
                   : (blockIdx.y == 2) ? v1 : g1;
  float* d = wt + (size_t)blockIdx.y * (8 * C_DIM);
  int c = blockIdx.x * 256 + threadIdx.x;    // grid.x = 8
  f32x4 lo = *(const f32x4*)(s + c * 8);
  f32x4 hi = *(const f32x4*)(s + c * 8 + 4);
  d[0 * C_DIM + c] = lo[0]; d[1 * C_DIM + c] = lo[1];
  d[2 * C_DIM + c] = lo[2]; d[3 * C_DIM + c] = lo[3];
  d[4 * C_DIM + c] = hi[0]; d[5 * C_DIM + c] = hi[1];
  d[6 * C_DIM + c] = hi[2]; d[7 * C_DIM + c] = hi[3];
}

// ---------------- mix + LoRA down: 2 rows per block (tables read once per pair) ----------------
__global__ __launch_bounds__(256)
void mix_lora_k(const float* __restrict__ x,
                const float* __restrict__ xrw, const float* __restrict__ xww,
                const float* __restrict__ xkw, const float* __restrict__ xvw,
                const float* __restrict__ xaw, const float* __restrict__ xgw,
                const float* __restrict__ wt,   // 4 transposed tables, 8xC each
                u16* __restrict__ xr_bf, u16* __restrict__ xk_bf,
                u16* __restrict__ xv_bf, float* __restrict__ lora8) {
  const int pr = blockIdx.x * 2;          // rows pr, pr+1 (t0 even)
  const int t0 = pr & (T_LEN - 1);
  const int tid = threadIdx.x;
  const float* xr0 = x + (size_t)pr * C_DIM;
  const float* xr1 = xr0 + C_DIM;
  float wl0[8], al0[8], vl0[8], gl0[8];
  float wl1[8], al1[8], vl1[8], gl1[8];
  #pragma unroll
  for (int l = 0; l < 8; ++l) {
    wl0[l] = 0.f; al0[l] = 0.f; vl0[l] = 0.f; gl0[l] = 0.f;
    wl1[l] = 0.f; al1[l] = 0.f; vl1[l] = 0.f; gl1[l] = 0.f;
  }
  #pragma unroll
  for (int ii = 0; ii < 8; ++ii) {
    const int c = ii * 256 + tid;
    float x0 = xr0[c], x1 = xr1[c];
    float xm = t0 ? xr0[c - C_DIM] : 0.f;
    float dx0 = xm - x0;
    float dx1 = x0 - x1;
    float mr = xrw[c], mw = xww[c], mk = xkw[c];
    float mv = xvw[c], ma = xaw[c], mg = xgw[c];
    float xw0 = fmaf(dx0, mw, x0), xw1 = fmaf(dx1, mw, x1);
    float xa0 = fmaf(dx0, ma, x0), xa1 = fmaf(dx1, ma, x1);
    float xv0 = fmaf(dx0, mv, x0), xv1 = fmaf(dx1, mv, x1);
    float xg0 = fmaf(dx0, mg, x0), xg1 = fmaf(dx1, mg, x1);
    xr_bf[(size_t)pr * C_DIM + c] = f2bf(fmaf(dx0, mr, x0));
    xr_bf[(size_t)(pr + 1) * C_DIM + c] = f2bf(fmaf(dx1, mr, x1));
    xk_bf[(size_t)pr * C_DIM + c] = f2bf(fmaf(dx0, mk, x0));
    xk_bf[(size_t)(pr + 1) * C_DIM + c] = f2bf(fmaf(dx1, mk, x1));
    xv_bf[(size_t)pr * C_DIM + c] = f2bf(xv0);
    xv_bf[(size_t)(pr + 1) * C_DIM + c] = f2bf(xv1);
    #pragma unroll
    for (int l = 0; l < 8; ++l) {
      float tw = wt[l * C_DIM + c];
      float ta = wt[16384 + l * C_DIM + c];
      float tv = wt[32768 + l * C_DIM + c];
      float tg = wt[49152 + l * C_DIM + c];
      wl0[l] = fmaf(xw0, tw, wl0[l]); wl1[l] = fmaf(xw1, tw, wl1[l]);
      al0[l] = fmaf(xa0, ta, al0[l]); al1[l] = fmaf(xa1, ta, al1[l]);
      vl0[l] = fmaf(xv0, tv, vl0[l]); vl1[l] = fmaf(xv1, tv, vl1[l]);
      gl0[l] = fmaf(xg0, tg, gl0[l]); gl1[l] = fmaf(xg1, tg, gl1[l]);
    }
  }
  __shared__ __attribute__((aligned(16))) float red2[2][16][32];
  const int row = tid >> 4;
  // row-reduce (16 lanes) all partials via DPP — pure VALU
  f32x4 t0v, t1v;
  #pragma unroll
  for (int half = 0; half < 2; ++half) {
    float* wl = half ? wl1 : wl0;
    float* al = half ? al1 : al0;
    float* vl = half ? vl1 : vl0;
    float* gl = half ? gl1 : gl0;
    t0v = red16v((f32x4){wl[0], wl[1], wl[2], wl[3]});
    t1v = red16v((f32x4){wl[4], wl[5], wl[6], wl[7]});
    if ((tid & 15) == 0) {
      *(f32x4*)&red2[half][row][0] = t0v; *(f32x4*)&red2[half][row][4] = t1v;
    }
    t0v = red16v((f32x4){al[0], al[1], al[2], al[3]});
    t1v = red16v((f32x4){al[4], al[5], al[6], al[7]});
    if ((tid & 15) == 0) {
      *(f32x4*)&red2[half][row][8] = t0v; *(f32x4*)&red2[half][row][12] = t1v;
    }
    t0v = red16v((f32x4){vl[0], vl[1], vl[2], vl[3]});
    t1v = red16v((f32x4){vl[4], vl[5], vl[6], vl[7]});
    if ((tid & 15) == 0) {
      *(f32x4*)&red2[half][row][16] = t0v; *(f32x4*)&red2[half][row][20] = t1v;
    }
    t0v = red16v((f32x4){gl[0], gl[1], gl[2], gl[3]});
    t1v = red16v((f32x4){gl[4], gl[5], gl[6], gl[7]});
    if ((tid & 15) == 0) {
      *(f32x4*)&red2[half][row][24] = t0v; *(f32x4*)&red2[half][row][28] = t1v;
    }
  }
  __syncthreads();
  if (tid < 64) {
    const int rw = tid >> 5, idx = tid & 31;
    float s = 0.f;
    #pragma unroll
    for (int r = 0; r < 16; ++r) s += red2[rw][r][idx];
    int mat = idx >> 3;
    if (mat == 0) s = tanhf(s);
    else if (mat == 3) s = 1.f / (1.f + expf(-s));
    lora8[(size_t)(pr + rw) * 32 + idx] = s;
  }
}

// ---------------- 256x256 8-wave MFMA GEMM: BK=32, quad buffer, depth-3, 1 barrier/tile ----------------
// Scatter staging: k -> bytes 128..159, r -> 160..191, v -> 192..223 of the
// record (all 32B-contiguous; dec/y slot doubles as k/r staging until
// post_gemm consumes it).
__device__ __forceinline__ int swzslot(int row, int slot) {
  return slot ^ ((row >> 1) & 3);
}

__global__ __launch_bounds__(512)
void gemm8_k(const u16* __restrict__ A0, const u16* __restrict__ A1,
             const u16* __restrict__ A2, const u16* __restrict__ B0,
             const u16* __restrict__ B1, const u16* __restrict__ B2,
             char* __restrict__ out, int pmode) {
  extern __shared__ __attribute__((aligned(16))) char smem[];
  // 4 buffers x 32 KB; buffer b: A u16[8192] at b*16384, B u16[8192] at +8192
  const int z = blockIdx.z;
  const u16* A = (z == 0) ? A0 : (z == 1) ? A1 : A2;
  const u16* Bw = (z == 0) ? B0 : (z == 1) ? B1 : B2;
  const int sbase = (z == 0) ? 128 : (z == 1) ? 160 : 192;
  const int tid = threadIdx.x;
  const int wv = tid >> 6, ln = tid & 63;
  const int wr = wv >> 2, wc = wv & 3;         // 2 x 4 wave grid
  // XCD-bijective swizzle of the 8x32 tile grid (nwg=256, 256%8==0)
  const int bid = blockIdx.x + (blockIdx.y << 3);
  const int sw = (bid & 7) * 32 + (bid >> 3);
  const int row0 = (sw >> 3) * 256, col0 = (sw & 7) * 256;
  const int s_rw = tid >> 2;
  const int s_slotL = (tid & 3) ^ ((s_rw >> 1) & 3);   // logical slot fetched
  int aoff[8], boff[4];
  #pragma unroll
  for (int m = 0; m < 8; ++m) {
    int row = wr * 128 + m * 16 + (ln & 15);
    aoff[m] = row * 32 + swzslot(row, ln >> 4) * 8;
  }
  #pragma unroll
  for (int n = 0; n < 4; ++n) {
    int row = wc * 64 + n * 16 + (ln & 15);
    boff[n] = row * 32 + swzslot(row, ln >> 4) * 8;
  }
  f32x4 acc[8][4];
  #pragma unroll
  for (int m = 0; m < 8; ++m)
    #pragma unroll
    for (int n = 0; n < 4; ++n) acc[m][n] = (f32x4){0.f, 0.f, 0.f, 0.f};

  auto bufA = [&](int b) -> u16* { return (u16*)smem + b * 16384; };
  auto bufB = [&](int b) -> u16* { return (u16*)smem + b * 16384 + 8192; };
  auto stageA = [&](int kt, int b, int rblk) {
    const u16* g = A + (size_t)(row0 + rblk * 128 + s_rw) * 2048 + kt * 32 + s_slotL * 8;
    gld16(g, bufA(b) + rblk * 4096 + wv * 512);
  };
  auto stageB = [&](int kt, int b, int rblk) {
    const u16* g = Bw + (size_t)(col0 + rblk * 128 + s_rw) * 2048 + kt * 32 + s_slotL * 8;
    gld16(g, bufB(b) + rblk * 4096 + wv * 512);
  };

  // prologue: tiles 0,1,2 into buffers 0,1,2 (4 loads/tile per wave, FIFO order)
  #pragma unroll
  for (int t = 0; t < 3; ++t) {
    stageA(t, t, 0); stageA(t, t, 1); stageB(t, t, 0); stageB(t, t, 1);
  }

  for (int kt = 0; kt < 64; ++kt) {
    // retire exactly tile kt's 4 loads; deeper tiles stay in flight
    if (kt < 62)      asm volatile("s_waitcnt vmcnt(8)" ::: "memory");
    else if (kt == 62) asm volatile("s_waitcnt vmcnt(4)" ::: "memory");
    else               asm volatile("s_waitcnt vmcnt(0)" ::: "memory");
    __builtin_amdgcn_s_barrier();
    const int b = kt & 3;
    const u16* Ab = bufA(b);
    const u16* Bb = bufB(b);
    const int b3 = (kt + 3) & 3;
    const bool st = kt <= 60;
    bf16x8 bf[4], af[4];
    #pragma unroll
    for (int n = 0; n < 4; ++n) bf[n] = *(const bf16x8*)(Bb + boff[n]);
    #pragma unroll
    for (int m = 0; m < 4; ++m) af[m] = *(const bf16x8*)(Ab + aoff[m]);
    if (st) { stageA(kt + 3, b3, 0); stageA(kt + 3, b3, 1); }
    __builtin_amdgcn_s_setprio(1);
    #pragma unroll
    for (int m = 0; m < 4; ++m)
      #pragma unroll
      for (int n = 0; n < 4; ++n)
        acc[m][n] = __builtin_amdgcn_mfma_f32_16x16x32_bf16(af[m], bf[n], acc[m][n], 0, 0, 0);
    __builtin_amdgcn_s_setprio(0);
    #pragma unroll
    for (int m = 0; m < 4; ++m) af[m] = *(const bf16x8*)(Ab + aoff[4 + m]);
    if (st) { stageB(kt + 3, b3, 0); stageB(kt + 3, b3, 1); }
    __builtin_amdgcn_s_setprio(1);
    #pragma unroll
    for (int m = 0; m < 4; ++m)
      #pragma unroll
      for (int n = 0; n < 4; ++n)
        acc[4 + m][n] = __builtin_amdgcn_mfma_f32_16x16x32_bf16(af[m], bf[n], acc[4 + m][n], 0, 0, 0);
    __builtin_amdgcn_s_setprio(0);
  }

  const int rowb = row0 + wr * 128 + ((ln >> 4) << 2);
  const int colb = col0 + wc * 64 + (ln & 15);
  #pragma unroll
  for (int m = 0; m < 8; ++m)
    #pragma unroll
    for (int n = 0; n < 4; ++n)
      #pragma unroll
      for (int qq = 0; qq < 4; ++qq) {
        int row = rowb + m * 16 + qq;
        int col = colb + n * 16;
        float val = acc[m][n][qq];
        if (pmode == 0) {
          ((float*)out)[(size_t)row * 2048 + col] = val;
        } else {
          int bq = row >> 12, tq = row & (T_LEN - 1);
          int hq = col >> 4, jq = col & 15;
          *(u16*)(out + (size_t)((bq * 128 + hq) * T_LEN + tq) * REC
                  + sbase + jq * 2) = f2bf(val);
        }
      }
}

// ---------------- post-GEMM: LoRA-up, decay, v-mix, kk-norm (coalesced module mapping) ----------------
// Reads k/r/v from staging (k@128, r@160, v@192), assembles packets, writes
// dec over the staging. Record's 16 channels live in one 16-lane group, so
// wave-lockstep orders staging reads before the dec overwrite.
__global__ __launch_bounds__(256)
void post_gemm_k(const float* __restrict__ v_first, const float* __restrict__ lora8,
                 const float* __restrict__ w0, const float* __restrict__ w2,
                 const float* __restrict__ a0, const float* __restrict__ a2,
                 const float* __restrict__ v0, const float* __restrict__ v2,
                 const float* __restrict__ k_k, const float* __restrict__ k_a,
                 char* __restrict__ packed) {
  const int tg = blockIdx.x;          // 0..1023 (4 t each)
  const int mo = blockIdx.y;          // module 0..31 (64 channels)
  const int bq = blockIdx.z;
  const int tid = threadIdx.x;
  const int wv = tid >> 6, ln = tid & 63;
  const int t = tg * 4 + wv;
  const int cc = ln & 15;
  const int hq = mo * 4 + (ln >> 4);
  const int c = mo * 64 + ln;
  char* pb = packed + (size_t)((bq * 128 + hq) * T_LEN + t) * REC;
  const int rr = bq * T_LEN + t;
  u32 kbits = *(const u16*)(pb + 128 + cc * 2);   // k staging
  u32 rbits = *(const u16*)(pb + 160 + cc * 2);   // r staging
  float kraw = bflo(kbits);
  float vraw = bflo(*(const u16*)(pb + 192 + cc * 2));
  float vf = v_first[(size_t)rr * C_DIM + c];
  const float* lo = lora8 + (size_t)rr * 32;
  float wr_ = w0[c], ar_ = a0[c], vr_ = v0[c];
  #pragma unroll
  for (int l = 0; l < 8; ++l) {
    wr_ = fmaf(lo[l], w2[l * C_DIM + c], wr_);
    ar_ = fmaf(lo[8 + l], a2[l * C_DIM + c], ar_);
    vr_ = fmaf(lo[16 + l], v2[l * C_DIM + c], vr_);
  }
  float w_ = -log1pf(expf(-wr_)) - 0.5f;
  float dec = expf(-expf(w_));
  float a_ = 1.f / (1.f + expf(-ar_));
  float vm = 1.f / (1.f + expf(-vr_));
  float vnew = fmaf(vf - vraw, vm, vraw);
  float kk = kraw * k_k[c];
  float ss = red16(kk * kk);
  ss += __shfl_xor(ss, 16);
  ss += __shfl_xor(ss, 32);
  float sc = 1.f / fmaxf(sqrtf(ss), 1e-8f);
  float kn = kk * sc;
  u16 wa = f2bf(-kn);
  u16 wb = f2bf(kn * a_);
  u16 wk = f2bf(kraw * fmaf(a_ - 1.f, k_a[c], 1.f));
  // packets: word0 = a|b, word1 = k|r
  *(u32*)(pb + cc * 8) = (u32)wa | ((u32)wb << 16);
  *(u32*)(pb + cc * 8 + 4) = (u32)wk | (rbits << 16);
  *(u16*)(pb + 192 + cc * 2) = f2bf(vnew);
  *(float*)(pb + 128 + cc * 4) = dec;              // overwrites k/r staging
}

// ---------------- sequential RWKV7 scan: 1 head / 4-wave block, 1 elem/lane ----------------
__device__ __forceinline__ void stage(const char* g, char* l, int wv, int ln) {
  gld16(g + wv * 1024 + ln * 16, l + wv * 1024);
  gld16(g + 4096 + wv * 1024 + ln * 16, l + 4096 + wv * 1024);
  gld16(g + 8192 + wv * 1024 + ln * 16, l + 8192 + wv * 1024);
  if (wv < 2) gld16(g + 12288 + wv * 1024 + ln * 16, l + 12288 + wv * 1024);
}

__global__ __launch_bounds__(256)
void scan_k(char* __restrict__ packed) {
  // 2 chunk halves + 1 KB pad so distance-4 over-reads stay in-bounds
  __shared__ __attribute__((aligned(16))) char bufm[2 * CHB + 1024];
  __shared__ __attribute__((aligned(16))) float ybuf[CH * 20];   // stride 20: bank-conflict-free dump
  const int hb = blockIdx.x;
  const int tid = threadIdx.x;
  const int wv = tid >> 6, ln = tid & 63;
  const int j = ln & 15;
  const int i = wv * 4 + (ln >> 4);
  char* src = packed + (size_t)hb * (T_LEN * REC);
  float S = 0.f;
  stage(src, bufm, wv, ln);
  const int NC = T_LEN / CH;
  for (int c = 0; c < NC; ++c) {
    asm volatile("s_waitcnt vmcnt(0)" ::: "memory");
    __syncthreads();
    if (c + 1 < NC)
      stage(src + (size_t)(c + 1) * CHB, bufm + ((c + 1) & 1) * CHB, wv, ln);
    const char* Bp = bufm + (c & 1) * CHB;
    const char* p0 = Bp + j * 8;         // [a|b][k|r] packet, +t*REC
    const char* pd = Bp + 128 + j * 4;   // dec f32
    const char* pv = Bp + 192 + i * 2;   // v bf16
    // preload steps 0..3
    u32x2 kq[4]; float dq[4]; u32 vq[4];
    #pragma unroll
    for (int s = 0; s < 4; ++s) {
      kq[s] = *(const u32x2*)(p0 + s * REC);
      dq[s] = *(const float*)(pd + s * REC);
      vq[s] = *(const u16*)(pv + s * REC);
    }
    float yq0 = 0.f, yq1 = 0.f, yq2 = 0.f, yq3 = 0.f;
    #pragma unroll
    for (int t = 0; t < CH; ++t) {
      const int st = t & 3;
      u32x2 kc = kq[st]; float dc = dq[st]; u32 vc = vq[st];
      // prefetch t+4 (tail over-reads land in pad; re-preloaded next chunk)
      kq[st] = *(const u32x2*)(p0 + (t + 4) * REC);
      dq[st] = *(const float*)(pd + (t + 4) * REC);
      vq[st] = *(const u16*)(pv + (t + 4) * REC);
      float a_ = bflo(kc[0]), b_ = bfhi(kc[0]);
      float k_ = bflo(kc[1]), r_ = bfhi(kc[1]);
      float v_ = bflo(vc);
      float sa = red16(S * a_);
      S = fmaf(S, dc, fmaf(sa, b_, v_ * k_));
      float yv = red16(S * r_);
      const bool own = (j == (t & 15));
      if ((t >> 4) == 0)      yq0 = own ? yv : yq0;
      else if ((t >> 4) == 1) yq1 = own ? yv : yq1;
      else if ((t >> 4) == 2) yq2 = own ? yv : yq2;
      else                    yq3 = own ? yv : yq3;
    }
    // dump register y to ybuf: value yqQ holds y for (t = Q*16 + j, row i)
    ybuf[(0 * 16 + j) * 20 + i] = yq0;
    ybuf[(1 * 16 + j) * 20 + i] = yq1;
    ybuf[(2 * 16 + j) * 20 + i] = yq2;
    ybuf[(3 * 16 + j) * 20 + i] = yq3;
    __syncthreads();
    // coalesced y flush: thread -> record tid>>2, 16B part tid&3
    {
      const int rec = tid >> 2, part = tid & 3;
      f32x4 y4 = *(const f32x4*)(ybuf + rec * 20 + part * 4);
      *(f32x4*)(src + (size_t)c * CHB + rec * REC + 128 + part * 16) = y4;
    }
  }
}

// ---------------- GroupNorm + residual + gate -> bf16 (coalesced module mapping) ----------------
__global__ __launch_bounds__(256)
void post_gn_k(const char* __restrict__ packed, const float* __restrict__ lora8,
               const float* __restrict__ g2, const float* __restrict__ ln_g,
               const float* __restrict__ ln_b, const float* __restrict__ r_k,
               u16* __restrict__ og) {
  const int tg = blockIdx.x;          // 0..1023 (4 t each)
  const int mo = blockIdx.y;          // module 0..31 (64 channels)
  const int bq = blockIdx.z;
  const int tid = threadIdx.x;
  const int wv = tid >> 6, ln = tid & 63;
  const int t = tg * 4 + wv;
  const int cc = ln & 15;
  const int hq = mo * 4 + (ln >> 4);
  const int c = mo * 64 + ln;
  const char* pb = packed + (size_t)((bq * 128 + hq) * T_LEN + t) * REC;
  u32 kr = *(const u32*)(pb + cc * 8 + 4);
  float kv = bflo(kr), rv = bfhi(kr);
  float vv = bflo(*(const u16*)(pb + 192 + cc * 2));
  float o = *(const float*)(pb + 128 + cc * 4);
  const int rr = bq * T_LEN + t;
  const float* lo = lora8 + (size_t)rr * 32 + 24;
  float gg = 0.f;
  #pragma unroll
  for (int l = 0; l < 8; ++l) gg = fmaf(lo[l], g2[l * C_DIM + c], gg);
  float s1 = red16(o);
  float s2 = red16(o * o);
  float srk = red16(rv * kv * r_k[c]);
  s1 += __shfl_xor(s1, 16); s2 += __shfl_xor(s2, 16); srk += __shfl_xor(srk, 16);
  s1 += __shfl_xor(s1, 32); s2 += __shfl_xor(s2, 32); srk += __shfl_xor(srk, 32);
  float mu = s1 * (1.f / 64.f);
  float var = s2 * (1.f / 64.f) - mu * mu;
  float rstd = rsqrtf(var + 0.00064f);
  float on = fmaf((o - mu) * rstd, ln_g[c], ln_b[c]);
  float o2 = fmaf(srk, vv, on);
  og[(size_t)rr * C_DIM + c] = f2bf(o2 * gg);
}

extern "C" void kernel_launch(void* const* d_in, const int* in_sizes, int n_in,
                              void* d_out, int out_size, void* d_ws, size_t ws_size,
                              hipStream_t stream) {
  (void)in_sizes; (void)n_in; (void)out_size;
  const float* x      = (const float*)d_in[0];
  const float* v_first= (const float*)d_in[1];
  const float* x_r    = (const float*)d_in[2];
  const float* x_w    = (const float*)d_in[3];
  const float* x_k    = (const float*)d_in[4];
  const float* x_v    = (const float*)d_in[5];
  const float* x_a    = (const float*)d_in[6];
  const float* x_g    = (const float*)d_in[7];
  const float* w0     = (const float*)d_in[8];
  const float* w1     = (const float*)d_in[9];
  const float* w2     = (const float*)d_in[10];
  const float* a0     = (const float*)d_in[11];
  const float* a1     = (const float*)d_in[12];
  const float* a2     = (const float*)d_in[13];
  const float* v0     = (const float*)d_in[14];
  const float* v1     = (const float*)d_in[15];
  const float* v2     = (const float*)d_in[16];
  const float* g1     = (const float*)d_in[17];
  const float* g2     = (const float*)d_in[18];
  const float* k_k    = (const float*)d_in[19];
  const float* k_a    = (const float*)d_in[20];
  const float* r_k    = (const float*)d_in[21];
  const float* Wr     = (const float*)d_in[22];
  const float* Wk     = (const float*)d_in[23];
  const float* Wv     = (const float*)d_in[24];
  const float* Wo     = (const float*)d_in[25];
  const float* ln_g   = (const float*)d_in[26];
  const float* ln_b   = (const float*)d_in[27];

  if (ws_size < 370147328ull) return;
  char* ws = (char*)d_ws;
  u16* Wr_bf = (u16*)(ws + 0);            //  8 MB each, contiguous (conv indexes)
  u16* Wk_bf = Wr_bf + 4194304;
  u16* Wv_bf = Wk_bf + 4194304;
  u16* Wo_bf = Wv_bf + 4194304;
  u16* xr_bf = (u16*)(ws + 33554432);     // 32 MB each
  u16* xk_bf = xr_bf + 16777216;
  u16* xv_bf = xk_bf + 16777216;
  float* lora8 = (float*)(ws + 134217728); // 1 MB
  char* packed = ws + 135266304;           // 224 MB
  float* wt = (float*)packed;              // transposed LoRA tables (256 KB),
                                           // consumed before gemms overwrite
  u16* og = xr_bf;                         // reuse (dead after r-GEMM)
  float* out = (float*)d_out;

  (void)hipFuncSetAttribute((const void*)gemm8_k,
                            hipFuncAttributeMaxDynamicSharedMemorySize, 131072);

  conv_bf16_k<<<dim3(2048, 4), 256, 0, stream>>>(Wr, Wk, Wv, Wo, Wr_bf);
  trans_lora_k<<<dim3(8, 4), 256, 0, stream>>>(w1, a1, v1, g1, wt);

  mix_lora_k<<<4096, 256, 0, stream>>>(x, x_r, x_w, x_k, x_v, x_a, x_g,
                                       wt, xr_bf, xk_bf, xv_bf, lora8);

  gemm8_k<<<dim3(8, 32, 3), 512, 131072, stream>>>(xk_bf, xr_bf, xv_bf,
                                                   Wk_bf, Wr_bf, Wv_bf,
                                                   packed, 1);

  post_gemm_k<<<dim3(1024, 32, 2), 256, 0, stream>>>(v_first, lora8, w0, w2,
                                                     a0, a2, v0, v2,
                                                     k_k, k_a, packed);

  scan_k<<<256, 256, 0, stream>>>(packed);

  post_gn_k<<<dim3(1024, 32, 2), 256, 0, stream>>>(packed, lora8, g2,
                                                   ln_g, ln_b, r_k, og);

  gemm8_k<<<dim3(8, 32, 1), 512, 131072, stream>>>(og, og, og,
                                                   Wo_bf, Wo_bf, Wo_bf,
                                                   (char*)out, 0);

  hipMemcpyAsync(out + 16777216, v_first, (size_t)16777216 * 4,
                 hipMemcpyDeviceToDevice, stream);
}